// Round 12
// baseline (115.339 us; speedup 1.0000x reference)
//
#include <hip/hip_runtime.h>
#include <hip/hip_bf16.h>
#include <stdint.h>

// NeighborhoodAttention1D: B=4, L=4096, C=512, H=16, hd=32, K=13
// cvt(x)->bf16 ; pack W->frag-order ; GEMM1/GEMM2 (A-LDS dbuf + B reg-dbuf,
// single-barrier tile) ; natt

typedef __attribute__((ext_vector_type(8))) short short8;   // 8 x bf16 frag
typedef __attribute__((ext_vector_type(4))) float f32x4;    // MFMA C/D frag
typedef __attribute__((ext_vector_type(8))) unsigned short u16x8;
typedef __attribute__((ext_vector_type(4))) float float4v;

#define NB 4
#define NL 4096
#define NC 512
#define NH 16
#define HD 32
#define KW 13
#define KHALF 6
#define NM (NB*NL)   // 16384 rows

__device__ __forceinline__ float b2f(unsigned short u) {
  union { unsigned int i; float f; } x; x.i = ((unsigned int)u) << 16; return x.f;
}
__device__ __forceinline__ unsigned short f2b(float f) {
  __hip_bfloat16 h = __float2bfloat16(f);   // RNE
  return __builtin_bit_cast(unsigned short, h);
}
__device__ __forceinline__ void gll16(const void* g, unsigned short* l) {
  __builtin_amdgcn_global_load_lds(
      (const __attribute__((address_space(1))) void*)g,
      (__attribute__((address_space(3))) void*)l, 16, 0, 0);
}

// ---------------- fp32 -> bf16 convert (x), 8 elems/thread ----------------
__global__ __launch_bounds__(256) void cvt_f32_bf16(const float* __restrict__ in,
                                                    unsigned short* __restrict__ out) {
  long i = (long)blockIdx.x * 256 + threadIdx.x;
  const float4v* in4 = (const float4v*)in;
  float4v a = in4[i * 2];
  float4v b = in4[i * 2 + 1];
  u16x8 u;
  u[0] = f2b(a.x); u[1] = f2b(a.y); u[2] = f2b(a.z); u[3] = f2b(a.w);
  u[4] = f2b(b.x); u[5] = f2b(b.y); u[6] = f2b(b.z); u[7] = f2b(b.w);
  ((u16x8*)out)[i] = u;
}

// ------ pack both weights -> fragment-ordered bf16 (single launch) --------
// group g: n = tn*128 + wn*64 + nj*16 + (lane&15), k = kt*64+(kb*4+(lane>>4))*8+e
__device__ __forceinline__ void pack_one(const float* __restrict__ W,
                                         unsigned short* __restrict__ Bf,
                                         int N, int g) {
  int lane = g & 63;
  int kb   = (g >> 6) & 1;
  int nj   = (g >> 7) & 3;
  int wn   = (g >> 9) & 1;
  int kt   = (g >> 10) & 7;
  int tn   = g >> 13;
  int n  = tn * 128 + wn * 64 + nj * 16 + (lane & 15);
  int k0 = kt * 64 + (kb * 4 + (lane >> 4)) * 8;
  u16x8 u;
  #pragma unroll
  for (int e = 0; e < 8; ++e) u[e] = f2b(W[(long)(k0 + e) * N + n]);
  ((u16x8*)Bf)[g] = u;
}
__global__ __launch_bounds__(256)
void pack_both(const float* __restrict__ W1, unsigned short* __restrict__ Bf1,
               const float* __restrict__ W2, unsigned short* __restrict__ Bf2) {
  int g = blockIdx.x * 256 + threadIdx.x;      // 512 blocks = 131072 threads
  if (g < 98304) pack_one(W1, Bf1, 1536, g);
  else           pack_one(W2, Bf2, 512, g - 98304);
}

#define BAR() __builtin_amdgcn_s_barrier()
#define LGK0() do { asm volatile("s_waitcnt lgkmcnt(0)" ::: "memory"); \
                    __builtin_amdgcn_sched_barrier(0); } while (0)
#define VM(N) asm volatile("s_waitcnt vmcnt(" #N ")" ::: "memory")

// ====== 128x128 bf16 GEMM: A-LDS dbuf (gll16) + B reg-dbuf, 1 BAR/tile =====
// C[M,N] = A[M,K]*W + bias (W frag-packed). K=512 -> 8 K-tiles of 64.
// 256 thr = 4 waves (2Mx2N), per-wave 64x64 = acc[4][4]. LDS 32KB -> 3 blk/CU.
// R11 post-mortem: R8's VM(4) waited on B(kt) issued ~100cy earlier (L2
// latency exposed every tile). Fix: B(kt+1) -> regs at tile kt start
// (bfA/bfB alternate; ~1 full tile of slack, compiler-tracked), and ONE
// barrier/tile: LDBG(kt+1) | LDA | lgkm0 | VM | BAR | stage A(kt+2) | MFMA.
//   - WAR on buf kt&1: all waves' LDA drained (lgkm0) before BAR; stage after.
//   - Publication of A(kt+1) (staged tile kt-1): VM retires it in every wave
//     pre-BAR -> visible to tile kt+1's LDA.
// vmcnt ledger (issue order: prologue A(0)4,A(1)4,B(0)8; tile kt issues
// B(kt+1)8 then A(kt+2)4):
//   prologue VM(12) -> A(0) landed.
//   tile0: outstanding {A(1)4,B(0)8,B(1)8}=20 -> VM(16) retires A(1).
//   tiles1-6 steady: {B(kt)8,A(kt+1)4,B(kt+1)8}=20 -> VM(8) retires
//     B(kt)+A(kt+1) (in-order), leaves B(kt+1). MFMA's bf already landed.
//   tile6: VM(8) retires A(7). tile7: nothing to wait (compiler waits bfB).
// Swizzle: chunk ^= (row&7), both-sides (R7/R8-verified: 0 bank conflicts).

__device__ __forceinline__ void stage_tileA(const unsigned short* __restrict__ G,
                                            long rowBase, int K, int kt,
                                            unsigned short* ldsDst, int tid) {
  int r  = tid >> 3;                       // 0..31
  int ch = (tid & 7) ^ (r & 7);            // inverse-swizzled source chunk
  const unsigned short* s0 = G + (rowBase + r) * (long)K + kt * 64 + ch * 8;
  unsigned short* d0 = ldsDst + tid * 8;
  #pragma unroll
  for (int q = 0; q < 4; ++q)              // rows r, r+32, r+64, r+96
    gll16(s0 + (long)32 * q * K, d0 + 2048 * q);
}

// af[ii][kb] <- A row wm*64 + ii*16 + lr, 16B chunk (kb*4+lk)^(row&7)
#define LDA_B16(ABASE) do { \
  const char* _ba = (const char*)(ABASE); \
  _Pragma("unroll") for (int ii = 0; ii < 4; ++ii) { \
    int _row = wm*64 + ii*16 + lr; \
    _Pragma("unroll") for (int kb = 0; kb < 2; ++kb) \
      af[ii][kb] = *(const short8*)(_ba + _row*128 + (((kb*4+lk) ^ lr7) * 16)); \
  } \
} while (0)

// BF[nj][kb] <- packed B frags for K-tile KT (8 coalesced 16B loads, L2-hot)
#define LDBG_TO(BF, KT) do { \
  const short8* _bp = (const short8*)(Bfw + (long)(KT) * 8192) + lane; \
  _Pragma("unroll") for (int nj = 0; nj < 4; ++nj) \
    _Pragma("unroll") for (int kb = 0; kb < 2; ++kb) \
      BF[nj][kb] = _bp[(nj*2 + kb) * 64]; \
} while (0)

#define MMA_ALL(BF) do { \
  __builtin_amdgcn_s_setprio(1); \
  _Pragma("unroll") for (int ii = 0; ii < 4; ++ii) \
    _Pragma("unroll") for (int jj = 0; jj < 4; ++jj) \
      _Pragma("unroll") for (int kb = 0; kb < 2; ++kb) \
        acc[ii][jj] = __builtin_amdgcn_mfma_f32_16x16x32_bf16( \
            af[ii][kb], BF[jj][kb], acc[ii][jj], 0, 0, 0); \
  __builtin_amdgcn_s_setprio(0); \
} while (0)

// One K-tile: BFC = current B regs, BFN = next B regs
#define GT(ABUF, KT, BFC, BFN, DO_LDBG, STG, VMARG) do { \
  if (DO_LDBG) LDBG_TO(BFN, (KT) + 1); \
  LDA_B16(ABUF); \
  LGK0(); \
  VMARG; \
  BAR(); \
  if (STG) stage_tileA(Ag, mBase, K, (KT) + 2, ABUF, tid); \
  MMA_ALL(BFC); \
} while (0)

template<int OUT_BF16>
__global__ __launch_bounds__(256, 3)
void gemm128(const unsigned short* __restrict__ Ag,
             const unsigned short* __restrict__ Bf,
             const float* __restrict__ bias,
             void* __restrict__ Cout,
             int M, int N, int K, int tilesN) {
  __shared__ __align__(16) unsigned short lds[16384];   // 32 KiB (A dbuf)

  int tid = threadIdx.x;
  int nwg = gridDim.x;                   // 1536 / 512, both %8==0
  int cpx = nwg >> 3;
  int wg  = ((int)blockIdx.x & 7) * cpx + ((int)blockIdx.x >> 3);  // XCD swizzle
  int tm = wg / tilesN, tn = wg % tilesN;
  long mBase = (long)tm * 128;
  long nBase = (long)tn * 128;

  int lane = tid & 63, wave = tid >> 6;
  int wm = wave >> 1, wn = wave & 1;
  int lr = lane & 15, lk = lane >> 4, lr7 = lr & 7;

  const unsigned short* Bfw = Bf + (long)tn * 65536 + wn * 4096;

  unsigned short* A0 = lds;              // buf0 A (128x64 bf16)
  unsigned short* A1 = lds + 8192;       // buf1 A

  f32x4 acc[4][4];
  #pragma unroll
  for (int i = 0; i < 4; ++i)
    #pragma unroll
    for (int j = 0; j < 4; ++j) acc[i][j] = (f32x4){0.f, 0.f, 0.f, 0.f};

  short8 af[4][2], bfA[4][2], bfB[4][2];

  // ---- prologue: A(0)->buf0, A(1)->buf1, B(0)->bfA ----
  stage_tileA(Ag, mBase, K, 0, A0, tid);
  stage_tileA(Ag, mBase, K, 1, A1, tid);
  LDBG_TO(bfA, 0);
  VM(12);                      // A(0) landed; {A(1)4,B(0)8} in flight
  BAR();

  GT(A0, 0, bfA, bfB, 1, 1, VM(16));   // retire A(1)
  GT(A1, 1, bfB, bfA, 1, 1, VM(8));    // retire B(1)+A(2)
  GT(A0, 2, bfA, bfB, 1, 1, VM(8));
  GT(A1, 3, bfB, bfA, 1, 1, VM(8));
  GT(A0, 4, bfA, bfB, 1, 1, VM(8));
  GT(A1, 5, bfB, bfA, 1, 1, VM(8));
  GT(A0, 6, bfA, bfB, 1, 0, VM(8));    // retire A(7); B(7) in flight
  GT(A1, 7, bfB, bfA, 0, 0, (void)0);  // compiler waits bfB

  // ---- epilogue: C/D layout col = lane&15, row = (lane>>4)*4 + r --------
  long rowb = mBase + wm * 64 + (lane >> 4) * 4;
  int  colb = (int)nBase + wn * 64 + lr;
  if (OUT_BF16) {
    unsigned short* C = (unsigned short*)Cout;
    #pragma unroll
    for (int mi = 0; mi < 4; ++mi)
      #pragma unroll
      for (int nj = 0; nj < 4; ++nj) {
        int col = colb + nj * 16;
        float bv = bias[col];
        #pragma unroll
        for (int r = 0; r < 4; ++r)
          C[(rowb + mi * 16 + r) * (long)N + col] = f2b(acc[mi][nj][r] + bv);
      }
  } else {
    float* C = (float*)Cout;
    #pragma unroll
    for (int mi = 0; mi < 4; ++mi)
      #pragma unroll
      for (int nj = 0; nj < 4; ++nj) {
        int col = colb + nj * 16;
        float bv = bias[col];
        #pragma unroll
        for (int r = 0; r < 4; ++r)
          C[(rowb + mi * 16 + r) * (long)N + col] = acc[mi][nj][r] + bv;
      }
  }
}

// ---------------- neighborhood attention: 1 thread per (b,l,h) ------------
__global__ __launch_bounds__(256)
void natt(const unsigned short* __restrict__ qkv, const float* __restrict__ rpb,
          unsigned short* __restrict__ out) {
  int tid = blockIdx.x * 256 + threadIdx.x;
  int h = tid & 15;
  int l = (tid >> 4) & (NL - 1);
  int b = tid >> 16;
  const float scale = 0.17677669529663687f;

  long qb = ((long)(b * NL + l) * 3) * NC + h * HD;
  float q[HD];
  {
    const u16x8* q8 = (const u16x8*)(qkv + qb);
    #pragma unroll
    for (int w = 0; w < 4; ++w) {
      u16x8 u = q8[w];
      #pragma unroll
      for (int e = 0; e < 8; ++e) q[w * 8 + e] = b2f(u[e]) * scale;
    }
  }

  int ni = l - KHALF;
  if (ni < 0) ni = 0;
  if (ni > NL - KW) ni = NL - KW;
  const float* rb = rpb + h * (2 * KW - 1) + (ni - l + KW - 1);

  float p[KW];
  float mx = -1e30f;
  #pragma unroll
  for (int j = 0; j < KW; ++j) {
    long kb = ((long)(b * NL + ni + j) * 3 + 1) * NC + h * HD;
    const u16x8* k8 = (const u16x8*)(qkv + kb);
    float s = 0.f;
    #pragma unroll
    for (int w = 0; w < 4; ++w) {
      u16x8 u = k8[w];
      #pragma unroll
      for (int e = 0; e < 8; ++e) s += q[w * 8 + e] * b2f(u[e]);
    }
    s += rb[j];
    p[j] = s;
    mx = fmaxf(mx, s);
  }

  float sum = 0.f;
  #pragma unroll
  for (int j = 0; j < KW; ++j) { p[j] = __expf(p[j] - mx); sum += p[j]; }
  float inv = 1.0f / sum;

  float o[HD];
  #pragma unroll
  for (int d = 0; d < HD; ++d) o[d] = 0.f;
  #pragma unroll
  for (int j = 0; j < KW; ++j) {
    long vb = ((long)(b * NL + ni + j) * 3 + 2) * NC + h * HD;
    const u16x8* v8 = (const u16x8*)(qkv + vb);
    float wj = p[j] * inv;
    #pragma unroll
    for (int w = 0; w < 4; ++w) {
      u16x8 u = v8[w];
      #pragma unroll
      for (int e = 0; e < 8; ++e) o[w * 8 + e] += wj * b2f(u[e]);
    }
  }

  unsigned short* op = out + (long)(b * NL + l) * NC + h * HD;
  #pragma unroll
  for (int w = 0; w < 4; ++w) {
    u16x8 u;
    #pragma unroll
    for (int e = 0; e < 8; ++e) u[e] = f2b(o[w * 8 + e]);
    *((u16x8*)(op + w * 8)) = u;
  }
}

// ---------------------------------------------------------------------------
extern "C" void kernel_launch(void* const* d_in, const int* in_sizes, int n_in,
                              void* d_out, int out_size, void* d_ws, size_t ws_size,
                              hipStream_t stream) {
  const float* x      = (const float*)d_in[0];
  const float* qkv_w  = (const float*)d_in[1];
  const float* qkv_b  = (const float*)d_in[2];
  const float* rpb    = (const float*)d_in[3];
  const float* proj_w = (const float*)d_in[4];
  const float* proj_b = (const float*)d_in[5];
  float* out = (float*)d_out;

  char* ws = (char*)d_ws;
  unsigned short* xb   = (unsigned short*)(ws);              // 16,777,216 B
  unsigned short* Bf1  = (unsigned short*)(ws + 16777216);   //  1,572,864 B
  unsigned short* Bf2  = (unsigned short*)(ws + 18350080);   //    524,288 B
  unsigned short* qkvo = (unsigned short*)(ws + 18874368);   // 50,331,648 B
  unsigned short* attno= (unsigned short*)(ws + 69206016);   // 16,777,216 B

  cvt_f32_bf16<<<dim3(4096), dim3(256), 0, stream>>>(x, xb);
  pack_both<<<dim3(512), dim3(256), 0, stream>>>(qkv_w, Bf1, proj_w, Bf2);
  // qkv = x @ qkv_w + b   (bf16 out): 1536 blocks
  gemm128<1><<<dim3(1536), dim3(256), 0, stream>>>(xb, Bf1, qkv_b, qkvo,
                                                   NM, 1536, 512, 12);
  natt<<<dim3(1024), dim3(256), 0, stream>>>(qkvo, rpb, attno);
  // out = attn @ proj_w + b  (fp32 out): 512 blocks
  gemm128<0><<<dim3(512), dim3(256), 0, stream>>>(attno, Bf2, proj_b, out,
                                                  NM, 512, 512, 4);
}

// Round 13
// 107.158 us; speedup vs baseline: 1.0763x; 1.0763x over previous
//
#include <hip/hip_runtime.h>
#include <hip/hip_bf16.h>
#include <stdint.h>

// NeighborhoodAttention1D: B=4, L=4096, C=512, H=16, hd=32, K=13
// cvt+pack (merged) ; GEMM1/GEMM2 (A-LDS dbuf gll16, 4Mx1N waves, B->regs) ;
// natt

typedef __attribute__((ext_vector_type(8))) short short8;   // 8 x bf16 frag
typedef __attribute__((ext_vector_type(4))) float f32x4;    // MFMA C/D frag
typedef __attribute__((ext_vector_type(8))) unsigned short u16x8;
typedef __attribute__((ext_vector_type(4))) float float4v;

#define NB 4
#define NL 4096
#define NC 512
#define NH 16
#define HD 32
#define KW 13
#define KHALF 6
#define NM (NB*NL)   // 16384 rows

__device__ __forceinline__ float b2f(unsigned short u) {
  union { unsigned int i; float f; } x; x.i = ((unsigned int)u) << 16; return x.f;
}
__device__ __forceinline__ unsigned short f2b(float f) {
  __hip_bfloat16 h = __float2bfloat16(f);   // RNE
  return __builtin_bit_cast(unsigned short, h);
}
__device__ __forceinline__ void gll16(const void* g, unsigned short* l) {
  __builtin_amdgcn_global_load_lds(
      (const __attribute__((address_space(1))) void*)g,
      (__attribute__((address_space(3))) void*)l, 16, 0, 0);
}

// ---- merged: x->bf16 convert (blocks 0..4095) + W frag-pack (4096..4607) ---
// pack group g: n = tn*128 + nj*16 + (lane&15), k = kt*64 + (kb*4+(lane>>4))*8+e
//   g = (((tn*8 + kt)*8 + nj)*2 + kb)*64 + lane     [nj now 0..7: 4Mx1N waves]
__device__ __forceinline__ void pack_one(const float* __restrict__ W,
                                         unsigned short* __restrict__ Bf,
                                         int N, int g) {
  int lane = g & 63;
  int kb   = (g >> 6) & 1;
  int nj   = (g >> 7) & 7;
  int kt   = (g >> 10) & 7;
  int tn   = g >> 13;
  int n  = tn * 128 + nj * 16 + (lane & 15);
  int k0 = kt * 64 + (kb * 4 + (lane >> 4)) * 8;
  u16x8 u;
  #pragma unroll
  for (int e = 0; e < 8; ++e) u[e] = f2b(W[(long)(k0 + e) * N + n]);
  ((u16x8*)Bf)[g] = u;
}
__global__ __launch_bounds__(256)
void cvt_and_pack(const float* __restrict__ x, unsigned short* __restrict__ xb,
                  const float* __restrict__ W1, unsigned short* __restrict__ Bf1,
                  const float* __restrict__ W2, unsigned short* __restrict__ Bf2) {
  int bid = blockIdx.x;
  if (bid < 4096) {                      // x -> bf16, 8 elems/thread
    long i = (long)bid * 256 + threadIdx.x;
    const float4v* in4 = (const float4v*)x;
    float4v a = in4[i * 2];
    float4v b = in4[i * 2 + 1];
    u16x8 u;
    u[0] = f2b(a.x); u[1] = f2b(a.y); u[2] = f2b(a.z); u[3] = f2b(a.w);
    u[4] = f2b(b.x); u[5] = f2b(b.y); u[6] = f2b(b.z); u[7] = f2b(b.w);
    ((u16x8*)xb)[i] = u;
  } else {                               // weight packing (131072 groups)
    int g = (bid - 4096) * 256 + threadIdx.x;
    if (g < 98304) pack_one(W1, Bf1, 1536, g);
    else           pack_one(W2, Bf2, 512, g - 98304);
  }
}

#define BAR() __builtin_amdgcn_s_barrier()
#define LGK0() do { asm volatile("s_waitcnt lgkmcnt(0)" ::: "memory"); \
                    __builtin_amdgcn_sched_barrier(0); } while (0)
#define VM(N) asm volatile("s_waitcnt vmcnt(" #N ")" ::: "memory")

// ====== 128x128 bf16 GEMM: A-LDS dbuf (gll16), 4Mx1N waves, B in regs ======
// C[M,N] = A[M,K]*W + bias (W frag-packed). K=512 -> 8 K-tiles of 64.
// 256 thr = 4 waves, wave w owns rows [w*32, w*32+32) x ALL 128 cols:
//   -> each A-row read ONCE from LDS (R8's 2Mx2N layout read A 2x; LDS was
//      the saturated pipe: 32KB reads + 16KB writes vs 155cy MFMA).
//   Per-tile LDS now 16KB read + 16KB write (halved reads, zero redundancy).
// B: 16 frags (nj 0..7 x kb 0..1) in regs, 16 coalesced 16B L2 loads/tile.
// Regs: acc 2x8x4=64, bf 64, af 16, +misc ~= 170 -> bounds(256,2): cap 256,
//   spill impossible (R9/R11/R12 lesson); HW gives 3 waves/SIMD at <=170.
// Per K-tile (buf kt&1):  LDBG(kt) | LDA | lgkm0 | BAR | stage A(kt+2) |
//   VM | MFMA | BAR   [R8-identical sync skeleton, proven]
// vmcnt ledger (issue order: prologue A(0)4,A(1)4; tile kt: B(kt)16, A(kt+2)4):
//   prologue VM(4) -> A(0) landed, A(1) in flight.
//   tile kt (0..5): outstanding {A(kt+1)4, B(kt)16, A(kt+2)4}=24 -> VM(4)
//     retires A(kt+1)+B(kt) (in-order); trailing BAR publishes A(kt+1).
//   kt=6: {A(7)4, B(6)16} -> VM(0).  kt=7: {B(7)16} -> VM(0).
// Swizzle: chunk ^= (row&7), both-sides (R7/R8-verified: 0 bank conflicts).

__device__ __forceinline__ void stage_tileA(const unsigned short* __restrict__ G,
                                            long rowBase, int K, int kt,
                                            unsigned short* ldsDst, int tid) {
  int r  = tid >> 3;                       // 0..31
  int ch = (tid & 7) ^ (r & 7);            // inverse-swizzled source chunk
  const unsigned short* s0 = G + (rowBase + r) * (long)K + kt * 64 + ch * 8;
  unsigned short* d0 = ldsDst + tid * 8;
  #pragma unroll
  for (int q = 0; q < 4; ++q)              // rows r, r+32, r+64, r+96
    gll16(s0 + (long)32 * q * K, d0 + 2048 * q);
}

// af[ii][kb] <- A row wave*32 + ii*16 + lr, 16B chunk (kb*4+lk)^(row&7)
#define LDA_B16(ABASE) do { \
  const char* _ba = (const char*)(ABASE); \
  _Pragma("unroll") for (int ii = 0; ii < 2; ++ii) { \
    int _row = wave*32 + ii*16 + lr; \
    _Pragma("unroll") for (int kb = 0; kb < 2; ++kb) \
      af[ii][kb] = *(const short8*)(_ba + _row*128 + (((kb*4+lk) ^ lr7) * 16)); \
  } \
} while (0)

// bf[nj][kb] <- packed B frags for K-tile KT (16 coalesced 16B loads, L2-hot)
#define LDBG(KT) do { \
  const short8* _bp = (const short8*)(Bfw + (long)(KT) * 8192) + lane; \
  _Pragma("unroll") for (int nj = 0; nj < 8; ++nj) \
    _Pragma("unroll") for (int kb = 0; kb < 2; ++kb) \
      bf[nj][kb] = _bp[(nj*2 + kb) * 64]; \
} while (0)

#define MMA_ALL() do { \
  __builtin_amdgcn_s_setprio(1); \
  _Pragma("unroll") for (int ii = 0; ii < 2; ++ii) \
    _Pragma("unroll") for (int nj = 0; nj < 8; ++nj) \
      _Pragma("unroll") for (int kb = 0; kb < 2; ++kb) \
        acc[ii][nj] = __builtin_amdgcn_mfma_f32_16x16x32_bf16( \
            af[ii][kb], bf[nj][kb], acc[ii][nj], 0, 0, 0); \
  __builtin_amdgcn_s_setprio(0); \
} while (0)

#define GTILE(ABUF, KT, STG, VMARG) do { \
  LDBG(KT); \
  LDA_B16(ABUF); \
  LGK0(); \
  BAR(); \
  if (STG) stage_tileA(Ag, mBase, K, (KT) + 2, ABUF, tid); \
  VMARG; \
  MMA_ALL(); \
  BAR(); \
} while (0)

template<int OUT_BF16>
__global__ __launch_bounds__(256, 2)
void gemm128(const unsigned short* __restrict__ Ag,
             const unsigned short* __restrict__ Bf,
             const float* __restrict__ bias,
             void* __restrict__ Cout,
             int M, int N, int K, int tilesN) {
  __shared__ __align__(16) unsigned short lds[16384];   // 32 KiB (A dbuf)

  int tid = threadIdx.x;
  int nwg = gridDim.x;                   // 1536 / 512, both %8==0
  int cpx = nwg >> 3;
  int wg  = ((int)blockIdx.x & 7) * cpx + ((int)blockIdx.x >> 3);  // XCD swizzle
  int tm = wg / tilesN, tn = wg % tilesN;
  long mBase = (long)tm * 128;
  long nBase = (long)tn * 128;

  int lane = tid & 63, wave = tid >> 6;  // wave = M band (32 rows)
  int lr = lane & 15, lk = lane >> 4, lr7 = lr & 7;

  const unsigned short* Bfw = Bf + (long)tn * 65536;

  unsigned short* A0 = lds;              // buf0 A (128x64 bf16)
  unsigned short* A1 = lds + 8192;       // buf1 A

  f32x4 acc[2][8];
  #pragma unroll
  for (int i = 0; i < 2; ++i)
    #pragma unroll
    for (int j = 0; j < 8; ++j) acc[i][j] = (f32x4){0.f, 0.f, 0.f, 0.f};

  short8 af[2][2], bf[8][2];

  // ---- prologue: A(0)->buf0, A(1)->buf1 (8 gll16/thread) ----
  stage_tileA(Ag, mBase, K, 0, A0, tid);
  stage_tileA(Ag, mBase, K, 1, A1, tid);
  VM(4);                       // A(0) landed (A(1)'s 4 in flight)
  BAR();

  #pragma unroll 1
  for (int i = 0; i < 3; ++i) {
    GTILE(A0, 2*i,     true, VM(4));
    GTILE(A1, 2*i + 1, true, VM(4));
  }
  GTILE(A0, 6, false, VM(0));
  GTILE(A1, 7, false, VM(0));

  // ---- epilogue: C/D layout col = lane&15, row = (lane>>4)*4 + r --------
  long rowb = mBase + wave * 32 + (lane >> 4) * 4;
  int  colb = (int)nBase + lr;
  if (OUT_BF16) {
    unsigned short* C = (unsigned short*)Cout;
    #pragma unroll
    for (int mi = 0; mi < 2; ++mi)
      #pragma unroll
      for (int nj = 0; nj < 8; ++nj) {
        int col = colb + nj * 16;
        float bv = bias[col];
        #pragma unroll
        for (int r = 0; r < 4; ++r)
          C[(rowb + mi * 16 + r) * (long)N + col] = f2b(acc[mi][nj][r] + bv);
      }
  } else {
    float* C = (float*)Cout;
    #pragma unroll
    for (int mi = 0; mi < 2; ++mi)
      #pragma unroll
      for (int nj = 0; nj < 8; ++nj) {
        int col = colb + nj * 16;
        float bv = bias[col];
        #pragma unroll
        for (int r = 0; r < 4; ++r)
          C[(rowb + mi * 16 + r) * (long)N + col] = acc[mi][nj][r] + bv;
      }
  }
}

// ---------------- neighborhood attention: 1 thread per (b,l,h) ------------
__global__ __launch_bounds__(256)
void natt(const unsigned short* __restrict__ qkv, const float* __restrict__ rpb,
          unsigned short* __restrict__ out) {
  int tid = blockIdx.x * 256 + threadIdx.x;
  int h = tid & 15;
  int l = (tid >> 4) & (NL - 1);
  int b = tid >> 16;
  const float scale = 0.17677669529663687f;

  long qb = ((long)(b * NL + l) * 3) * NC + h * HD;
  float q[HD];
  {
    const u16x8* q8 = (const u16x8*)(qkv + qb);
    #pragma unroll
    for (int w = 0; w < 4; ++w) {
      u16x8 u = q8[w];
      #pragma unroll
      for (int e = 0; e < 8; ++e) q[w * 8 + e] = b2f(u[e]) * scale;
    }
  }

  int ni = l - KHALF;
  if (ni < 0) ni = 0;
  if (ni > NL - KW) ni = NL - KW;
  const float* rb = rpb + h * (2 * KW - 1) + (ni - l + KW - 1);

  float p[KW];
  float mx = -1e30f;
  #pragma unroll
  for (int j = 0; j < KW; ++j) {
    long kb = ((long)(b * NL + ni + j) * 3 + 1) * NC + h * HD;
    const u16x8* k8 = (const u16x8*)(qkv + kb);
    float s = 0.f;
    #pragma unroll
    for (int w = 0; w < 4; ++w) {
      u16x8 u = k8[w];
      #pragma unroll
      for (int e = 0; e < 8; ++e) s += q[w * 8 + e] * b2f(u[e]);
    }
    s += rb[j];
    p[j] = s;
    mx = fmaxf(mx, s);
  }

  float sum = 0.f;
  #pragma unroll
  for (int j = 0; j < KW; ++j) { p[j] = __expf(p[j] - mx); sum += p[j]; }
  float inv = 1.0f / sum;

  float o[HD];
  #pragma unroll
  for (int d = 0; d < HD; ++d) o[d] = 0.f;
  #pragma unroll
  for (int j = 0; j < KW; ++j) {
    long vb = ((long)(b * NL + ni + j) * 3 + 2) * NC + h * HD;
    const u16x8* v8 = (const u16x8*)(qkv + vb);
    float wj = p[j] * inv;
    #pragma unroll
    for (int w = 0; w < 4; ++w) {
      u16x8 u = v8[w];
      #pragma unroll
      for (int e = 0; e < 8; ++e) o[w * 8 + e] += wj * b2f(u[e]);
    }
  }

  unsigned short* op = out + (long)(b * NL + l) * NC + h * HD;
  #pragma unroll
  for (int w = 0; w < 4; ++w) {
    u16x8 u;
    #pragma unroll
    for (int e = 0; e < 8; ++e) u[e] = f2b(o[w * 8 + e]);
    *((u16x8*)(op + w * 8)) = u;
  }
}

// ---------------------------------------------------------------------------
extern "C" void kernel_launch(void* const* d_in, const int* in_sizes, int n_in,
                              void* d_out, int out_size, void* d_ws, size_t ws_size,
                              hipStream_t stream) {
  const float* x      = (const float*)d_in[0];
  const float* qkv_w  = (const float*)d_in[1];
  const float* qkv_b  = (const float*)d_in[2];
  const float* rpb    = (const float*)d_in[3];
  const float* proj_w = (const float*)d_in[4];
  const float* proj_b = (const float*)d_in[5];
  float* out = (float*)d_out;

  char* ws = (char*)d_ws;
  unsigned short* xb   = (unsigned short*)(ws);              // 16,777,216 B
  unsigned short* Bf1  = (unsigned short*)(ws + 16777216);   //  1,572,864 B
  unsigned short* Bf2  = (unsigned short*)(ws + 18350080);   //    524,288 B
  unsigned short* qkvo = (unsigned short*)(ws + 18874368);   // 50,331,648 B
  unsigned short* attno= (unsigned short*)(ws + 69206016);   // 16,777,216 B

  cvt_and_pack<<<dim3(4608), dim3(256), 0, stream>>>(x, xb, qkv_w, Bf1,
                                                     proj_w, Bf2);
  // qkv = x @ qkv_w + b   (bf16 out): 1536 blocks
  gemm128<1><<<dim3(1536), dim3(256), 0, stream>>>(xb, Bf1, qkv_b, qkvo,
                                                   NM, 1536, 512, 12);
  natt<<<dim3(1024), dim3(256), 0, stream>>>(qkvo, rpb, attno);
  // out = attn @ proj_w + b  (fp32 out): 512 blocks
  gemm128<0><<<dim3(512), dim3(256), 0, stream>>>(attno, Bf2, proj_b, out,
                                                  NM, 512, 512, 4);
}

// Round 14
// 93.574 us; speedup vs baseline: 1.2326x; 1.1452x over previous
//
#include <hip/hip_runtime.h>
#include <hip/hip_bf16.h>
#include <stdint.h>

// NeighborhoodAttention1D: B=4, L=4096, C=512, H=16, hd=32, K=13
// cvt+pack (merged, one launch) ; GEMM1/GEMM2 (R8-verbatim: A-LDS dbuf gll16,
// 2Mx2N waves, B frag-direct to regs) ; natt

typedef __attribute__((ext_vector_type(8))) short short8;   // 8 x bf16 frag
typedef __attribute__((ext_vector_type(4))) float f32x4;    // MFMA C/D frag
typedef __attribute__((ext_vector_type(8))) unsigned short u16x8;
typedef __attribute__((ext_vector_type(4))) float float4v;

#define NB 4
#define NL 4096
#define NC 512
#define NH 16
#define HD 32
#define KW 13
#define KHALF 6
#define NM (NB*NL)   // 16384 rows

__device__ __forceinline__ float b2f(unsigned short u) {
  union { unsigned int i; float f; } x; x.i = ((unsigned int)u) << 16; return x.f;
}
__device__ __forceinline__ unsigned short f2b(float f) {
  __hip_bfloat16 h = __float2bfloat16(f);   // RNE
  return __builtin_bit_cast(unsigned short, h);
}
__device__ __forceinline__ void gll16(const void* g, unsigned short* l) {
  __builtin_amdgcn_global_load_lds(
      (const __attribute__((address_space(1))) void*)g,
      (__attribute__((address_space(3))) void*)l, 16, 0, 0);
}

// ---- merged: x->bf16 convert (blocks 0..4095) + W frag-pack (4096..4607) ---
// R8 pack grouping: g = ((((tn*8+kt)*2+wn)*4+nj)*2+kb)*64 + lane
//   n = tn*128 + wn*64 + nj*16 + (lane&15), k = kt*64 + (kb*4+(lane>>4))*8 + e
__device__ __forceinline__ void pack_one(const float* __restrict__ W,
                                         unsigned short* __restrict__ Bf,
                                         int N, int g) {
  int lane = g & 63;
  int kb   = (g >> 6) & 1;
  int nj   = (g >> 7) & 3;
  int wn   = (g >> 9) & 1;
  int kt   = (g >> 10) & 7;
  int tn   = g >> 13;
  int n  = tn * 128 + wn * 64 + nj * 16 + (lane & 15);
  int k0 = kt * 64 + (kb * 4 + (lane >> 4)) * 8;
  u16x8 u;
  #pragma unroll
  for (int e = 0; e < 8; ++e) u[e] = f2b(W[(long)(k0 + e) * N + n]);
  ((u16x8*)Bf)[g] = u;
}
__global__ __launch_bounds__(256)
void cvt_and_pack(const float* __restrict__ x, unsigned short* __restrict__ xb,
                  const float* __restrict__ W1, unsigned short* __restrict__ Bf1,
                  const float* __restrict__ W2, unsigned short* __restrict__ Bf2) {
  int bid = blockIdx.x;
  if (bid < 4096) {                      // x -> bf16, 8 elems/thread
    long i = (long)bid * 256 + threadIdx.x;
    const float4v* in4 = (const float4v*)x;
    float4v a = in4[i * 2];
    float4v b = in4[i * 2 + 1];
    u16x8 u;
    u[0] = f2b(a.x); u[1] = f2b(a.y); u[2] = f2b(a.z); u[3] = f2b(a.w);
    u[4] = f2b(b.x); u[5] = f2b(b.y); u[6] = f2b(b.z); u[7] = f2b(b.w);
    ((u16x8*)xb)[i] = u;
  } else {                               // weight packing (131072 groups)
    int g = (bid - 4096) * 256 + threadIdx.x;
    if (g < 98304) pack_one(W1, Bf1, 1536, g);
    else           pack_one(W2, Bf2, 512, g - 98304);
  }
}

#define BAR() __builtin_amdgcn_s_barrier()
#define LGK0() do { asm volatile("s_waitcnt lgkmcnt(0)" ::: "memory"); \
                    __builtin_amdgcn_sched_barrier(0); } while (0)
#define VM(N) asm volatile("s_waitcnt vmcnt(" #N ")" ::: "memory")

// ====== R8-verbatim 128x128 GEMM: A-only LDS (32KB dbuf), B frag-direct ====
// C[M,N] = A[M,K]*W + bias, W frag-packed. K=512 -> 8 K-tiles of 64.
// 256 threads = 4 waves (2M x 2N), per-wave 64x64 out = acc[4][4].
// Regs: acc 64 + af 16 + bf 16 + addr ~= 110 -> VGPR 128 stable (R7/R8).
// R9/R11/R12/R13 lesson: any variant pushing live set past ~130 triggers
// compiler spill (R9/R12), load-sinking (R11) or live-range splitting (R13).
// Per iter kt (buf kt&1): LDBG(kt) | LDA | lgkm0 | BAR | stage A(kt+2) |
//   VM(4) | MFMA | BAR.
// vmcnt ledger (prologue A(0)4,A(1)4; tile kt issues B(kt)8, A(kt+2)4):
//   prologue VM(4) -> A(0) landed. tile kt (0..5): outstanding
//   {A(kt+1)4, B(kt)8, A(kt+2)4}=16 -> VM(4) retires A(kt+1)+B(kt);
//   end-BAR publishes A(kt+1). kt=6: {A(7)4,B(6)8} VM(0). kt=7: {B(7)8} VM(0).
// Swizzle: chunk ^= (row&7), both-sides (R2..R8-verified: 0 bank conflicts).

__device__ __forceinline__ void stage_tileA(const unsigned short* __restrict__ G,
                                            long rowBase, int K, int kt,
                                            unsigned short* ldsDst, int tid) {
  int r  = tid >> 3;                       // 0..31
  int ch = (tid & 7) ^ (r & 7);            // inverse-swizzled source chunk
  const unsigned short* s0 = G + (rowBase + r) * (long)K + kt * 64 + ch * 8;
  unsigned short* d0 = ldsDst + tid * 8;
  #pragma unroll
  for (int q = 0; q < 4; ++q)              // rows r, r+32, r+64, r+96
    gll16(s0 + (long)32 * q * K, d0 + 2048 * q);
}

// af[ii][kb] <- A row wm*64 + ii*16 + lr, 16B chunk (kb*4+lk)^(row&7)
#define LDA_B16(ABASE) do { \
  const char* _ba = (const char*)(ABASE); \
  _Pragma("unroll") for (int ii = 0; ii < 4; ++ii) { \
    int _row = wm*64 + ii*16 + lr; \
    _Pragma("unroll") for (int kb = 0; kb < 2; ++kb) \
      af[ii][kb] = *(const short8*)(_ba + _row*128 + (((kb*4+lk) ^ lr7) * 16)); \
  } \
} while (0)

// bf[nj][kb] <- packed B frags for K-tile KT (8 coalesced 16B loads, L2-hot)
#define LDBG(KT) do { \
  const short8* _bp = (const short8*)(Bfw + (long)(KT) * 8192) + lane; \
  _Pragma("unroll") for (int nj = 0; nj < 4; ++nj) \
    _Pragma("unroll") for (int kb = 0; kb < 2; ++kb) \
      bf[nj][kb] = _bp[(nj*2 + kb) * 64]; \
} while (0)

#define MMA_ALL() do { \
  __builtin_amdgcn_s_setprio(1); \
  _Pragma("unroll") for (int ii = 0; ii < 4; ++ii) \
    _Pragma("unroll") for (int jj = 0; jj < 4; ++jj) \
      _Pragma("unroll") for (int kb = 0; kb < 2; ++kb) \
        acc[ii][jj] = __builtin_amdgcn_mfma_f32_16x16x32_bf16( \
            af[ii][kb], bf[jj][kb], acc[ii][jj], 0, 0, 0); \
  __builtin_amdgcn_s_setprio(0); \
} while (0)

#define GTILE(ABUF, KT, STG, VMARG) do { \
  LDBG(KT); \
  LDA_B16(ABUF); \
  LGK0(); \
  BAR(); \
  if (STG) stage_tileA(Ag, mBase, K, (KT) + 2, ABUF, tid); \
  VMARG; \
  MMA_ALL(); \
  BAR(); \
} while (0)

template<int OUT_BF16>
__global__ __launch_bounds__(256, 3)
void gemm128(const unsigned short* __restrict__ Ag,
             const unsigned short* __restrict__ Bf,
             const float* __restrict__ bias,
             void* __restrict__ Cout,
             int M, int N, int K, int tilesN) {
  __shared__ __align__(16) unsigned short lds[16384];   // 32 KiB (A dbuf)

  int tid = threadIdx.x;
  int nwg = gridDim.x;                   // 1536 / 512, both %8==0
  int cpx = nwg >> 3;
  int wg  = ((int)blockIdx.x & 7) * cpx + ((int)blockIdx.x >> 3);  // XCD swizzle
  int tm = wg / tilesN, tn = wg % tilesN;
  long mBase = (long)tm * 128;
  long nBase = (long)tn * 128;

  int lane = tid & 63, wave = tid >> 6;
  int wm = wave >> 1, wn = wave & 1;
  int lr = lane & 15, lk = lane >> 4, lr7 = lr & 7;

  const unsigned short* Bfw = Bf + (long)tn * 65536 + wn * 4096;

  unsigned short* A0 = lds;              // buf0 A (128x64 bf16)
  unsigned short* A1 = lds + 8192;       // buf1 A

  f32x4 acc[4][4];
  #pragma unroll
  for (int i = 0; i < 4; ++i)
    #pragma unroll
    for (int j = 0; j < 4; ++j) acc[i][j] = (f32x4){0.f, 0.f, 0.f, 0.f};

  short8 af[4][2], bf[4][2];

  // ---- prologue: A(0)->buf0, A(1)->buf1 (8 gll16/thread) ----
  stage_tileA(Ag, mBase, K, 0, A0, tid);
  stage_tileA(Ag, mBase, K, 1, A1, tid);
  VM(4);                       // A(0) landed (A(1)'s 4 in flight)
  BAR();

  #pragma unroll 1
  for (int i = 0; i < 3; ++i) {
    GTILE(A0, 2*i,     true, VM(4));
    GTILE(A1, 2*i + 1, true, VM(4));
  }
  GTILE(A0, 6, false, VM(0));
  GTILE(A1, 7, false, VM(0));

  // ---- epilogue: C/D layout col = lane&15, row = (lane>>4)*4 + r --------
  long rowb = mBase + wm * 64 + (lane >> 4) * 4;
  int  colb = (int)nBase + wn * 64 + lr;
  if (OUT_BF16) {
    unsigned short* C = (unsigned short*)Cout;
    #pragma unroll
    for (int mi = 0; mi < 4; ++mi)
      #pragma unroll
      for (int nj = 0; nj < 4; ++nj) {
        int col = colb + nj * 16;
        float bv = bias[col];
        #pragma unroll
        for (int r = 0; r < 4; ++r)
          C[(rowb + mi * 16 + r) * (long)N + col] = f2b(acc[mi][nj][r] + bv);
      }
  } else {
    float* C = (float*)Cout;
    #pragma unroll
    for (int mi = 0; mi < 4; ++mi)
      #pragma unroll
      for (int nj = 0; nj < 4; ++nj) {
        int col = colb + nj * 16;
        float bv = bias[col];
        #pragma unroll
        for (int r = 0; r < 4; ++r)
          C[(rowb + mi * 16 + r) * (long)N + col] = acc[mi][nj][r] + bv;
      }
  }
}

// ---------------- neighborhood attention: 1 thread per (b,l,h) ------------
__global__ __launch_bounds__(256)
void natt(const unsigned short* __restrict__ qkv, const float* __restrict__ rpb,
          unsigned short* __restrict__ out) {
  int tid = blockIdx.x * 256 + threadIdx.x;
  int h = tid & 15;
  int l = (tid >> 4) & (NL - 1);
  int b = tid >> 16;
  const float scale = 0.17677669529663687f;

  long qb = ((long)(b * NL + l) * 3) * NC + h * HD;
  float q[HD];
  {
    const u16x8* q8 = (const u16x8*)(qkv + qb);
    #pragma unroll
    for (int w = 0; w < 4; ++w) {
      u16x8 u = q8[w];
      #pragma unroll
      for (int e = 0; e < 8; ++e) q[w * 8 + e] = b2f(u[e]) * scale;
    }
  }

  int ni = l - KHALF;
  if (ni < 0) ni = 0;
  if (ni > NL - KW) ni = NL - KW;
  const float* rb = rpb + h * (2 * KW - 1) + (ni - l + KW - 1);

  float p[KW];
  float mx = -1e30f;
  #pragma unroll
  for (int j = 0; j < KW; ++j) {
    long kb = ((long)(b * NL + ni + j) * 3 + 1) * NC + h * HD;
    const u16x8* k8 = (const u16x8*)(qkv + kb);
    float s = 0.f;
    #pragma unroll
    for (int w = 0; w < 4; ++w) {
      u16x8 u = k8[w];
      #pragma unroll
      for (int e = 0; e < 8; ++e) s += q[w * 8 + e] * b2f(u[e]);
    }
    s += rb[j];
    p[j] = s;
    mx = fmaxf(mx, s);
  }

  float sum = 0.f;
  #pragma unroll
  for (int j = 0; j < KW; ++j) { p[j] = __expf(p[j] - mx); sum += p[j]; }
  float inv = 1.0f / sum;

  float o[HD];
  #pragma unroll
  for (int d = 0; d < HD; ++d) o[d] = 0.f;
  #pragma unroll
  for (int j = 0; j < KW; ++j) {
    long vb = ((long)(b * NL + ni + j) * 3 + 2) * NC + h * HD;
    const u16x8* v8 = (const u16x8*)(qkv + vb);
    float wj = p[j] * inv;
    #pragma unroll
    for (int w = 0; w < 4; ++w) {
      u16x8 u = v8[w];
      #pragma unroll
      for (int e = 0; e < 8; ++e) o[w * 8 + e] += wj * b2f(u[e]);
    }
  }

  unsigned short* op = out + (long)(b * NL + l) * NC + h * HD;
  #pragma unroll
  for (int w = 0; w < 4; ++w) {
    u16x8 u;
    #pragma unroll
    for (int e = 0; e < 8; ++e) u[e] = f2b(o[w * 8 + e]);
    *((u16x8*)(op + w * 8)) = u;
  }
}

// ---------------------------------------------------------------------------
extern "C" void kernel_launch(void* const* d_in, const int* in_sizes, int n_in,
                              void* d_out, int out_size, void* d_ws, size_t ws_size,
                              hipStream_t stream) {
  const float* x      = (const float*)d_in[0];
  const float* qkv_w  = (const float*)d_in[1];
  const float* qkv_b  = (const float*)d_in[2];
  const float* rpb    = (const float*)d_in[3];
  const float* proj_w = (const float*)d_in[4];
  const float* proj_b = (const float*)d_in[5];
  float* out = (float*)d_out;

  char* ws = (char*)d_ws;
  unsigned short* xb   = (unsigned short*)(ws);              // 16,777,216 B
  unsigned short* Bf1  = (unsigned short*)(ws + 16777216);   //  1,572,864 B
  unsigned short* Bf2  = (unsigned short*)(ws + 18350080);   //    524,288 B
  unsigned short* qkvo = (unsigned short*)(ws + 18874368);   // 50,331,648 B
  unsigned short* attno= (unsigned short*)(ws + 69206016);   // 16,777,216 B

  cvt_and_pack<<<dim3(4608), dim3(256), 0, stream>>>(x, xb, qkv_w, Bf1,
                                                     proj_w, Bf2);
  // qkv = x @ qkv_w + b   (bf16 out): 1536 blocks
  gemm128<1><<<dim3(1536), dim3(256), 0, stream>>>(xb, Bf1, qkv_b, qkvo,
                                                   NM, 1536, 512, 12);
  natt<<<dim3(1024), dim3(256), 0, stream>>>(qkvo, rpb, attno);
  // out = attn @ proj_w + b  (fp32 out): 512 blocks
  gemm128<0><<<dim3(512), dim3(256), 0, stream>>>(attno, Bf2, proj_b, out,
                                                  NM, 512, 512, 4);
}